// Round 4
// baseline (414.426 us; speedup 1.0000x reference)
//
#include <hip/hip_runtime.h>
#include <math.h>

// E8 lattice quantizer, pair-cooperative layout + nontemporal streaming.
// E8 = D8 ∪ (D8 + 1/2); per 8-float row quantize against both cosets, keep
// the nearer (y2 only on STRICT win).
//
// Layout: one thread per float4 (half-row). Lane l loads element l -> every
// load/store instruction is perfectly coalesced (16 B lane stride). Lanes
// (2j, 2j+1) of a wave cooperate on row j via __shfl_xor(.,1).
// Pure one-pass stream, zero reuse -> nontemporal hints skip cache alloc.
// NOTE: nontemporal builtins need a clang-native vector type, not HIP's
// float4 class -> v4f ext_vector alias for the memory ops.
//
// Exactness invariants (absmax==0.0 in rounds 1 and 2):
//  - rintf == jnp.round (half-to-even)
//  - parity shortcut: g = f±1 at one coord => sum(g) even <=> sum(f) odd
//  - argmax FIRST index wins ties: local scans strict >, cross-lane tie to
//    low lane (its indices 0..3 precede the hi lane's 4..7)
//  - distance sum in exact left-to-right order: low lane computes the
//    e0²..e3² prefix, hi lane continues with e4²..e7², no FMA contraction.

typedef float v4f __attribute__((ext_vector_type(4)));

__device__ __forceinline__ float sx1(float v) { return __shfl_xor(v, 1, 64); }

__global__ __launch_bounds__(256) void e8_quant_pair(
    const v4f* __restrict__ in, v4f* __restrict__ out, int n4)
{
#pragma clang fp contract(off)
    int t = blockIdx.x * blockDim.x + threadIdx.x;
    if (t >= n4) return;
    const bool hi = (t & 1) != 0;   // hi lane holds coords 4..7 of its row

    v4f v = __builtin_nontemporal_load(&in[t]);
    float x[4] = {v.x, v.y, v.z, v.w};

    float y[2][4];
#pragma unroll
    for (int c = 0; c < 2; ++c) {
        const float h = c ? 0.5f : 0.0f;
        float f[4], d[4];
#pragma unroll
        for (int j = 0; j < 4; ++j) {
            float xc = x[j] - h;          // exact (0.5 exact), same op as ref
            f[j] = rintf(xc);             // round-half-to-even
            d[j] = xc - f[j];             // exact
        }
        // local argmax |d|, first index wins (strict > replaces)
        float best = fabsf(d[0]); float dk = d[0]; int k = 0;
#pragma unroll
        for (int j = 1; j < 4; ++j) {
            float a = fabsf(d[j]);
            bool gt = a > best;
            best = gt ? a : best; dk = gt ? d[j] : dk; k = gt ? j : k;
        }
        float ls = ((f[0] + f[1]) + f[2]) + f[3];   // exact small integers
        float obest = sx1(best);
        float osum  = sx1(ls);
        // global winner: low lane wins ties (global first index)
        bool win = hi ? (best > obest) : (best >= obest);
        float tot = ls + osum;                       // exact
        int par = ((int)tot) & 1;                    // parity OK for negatives
        float fix = (dk < 0.0f) ? -1.0f : 1.0f;      // dk==0 -> +1 (matches ref)
        float add = (win && par) ? fix : 0.0f;
#pragma unroll
        for (int j = 0; j < 4; ++j)
            y[c][j] = (f[j] + ((j == k) ? add : 0.0f)) + h;  // +h exact
    }

    // distance sums, exact reference (left-to-right) association
    float s[2];
#pragma unroll
    for (int c = 0; c < 2; ++c) {
        float eq[4];
#pragma unroll
        for (int j = 0; j < 4; ++j) { float e = x[j] - y[c][j]; eq[j] = e * e; }
        float pl = (((0.0f + eq[0]) + eq[1]) + eq[2]) + eq[3];  // low-lane prefix
        float q = sx1(pl);                    // hi lane receives low's prefix
        float th = (((q + eq[0]) + eq[1]) + eq[2]) + eq[3];  // hi: +e4²..e7²
        float r = sx1(th);                    // low lane receives hi's total
        s[c] = hi ? th : r;                   // both lanes: exact sequential total
    }

    bool take2 = sqrtf(s[1]) < sqrtf(s[0]);   // strict: ties keep y1

    v4f o;
    o.x = take2 ? y[1][0] : y[0][0];
    o.y = take2 ? y[1][1] : y[0][1];
    o.z = take2 ? y[1][2] : y[0][2];
    o.w = take2 ? y[1][3] : y[0][3];
    __builtin_nontemporal_store(o, &out[t]);
}

extern "C" void kernel_launch(void* const* d_in, const int* in_sizes, int n_in,
                              void* d_out, int out_size, void* d_ws, size_t ws_size,
                              hipStream_t stream) {
    const v4f* x = (const v4f*)d_in[0];
    v4f* o = (v4f*)d_out;
    int n4 = in_sizes[0] / 4;                 // one thread per float4 (half-row)
    const int block = 256;
    const int grid = (n4 + block - 1) / block;
    e8_quant_pair<<<grid, block, 0, stream>>>(x, o, n4);
}